// Round 1
// baseline (1336.425 us; speedup 1.0000x reference)
//
#include <hip/hip_runtime.h>
#include <cmath>

typedef short short8 __attribute__((ext_vector_type(8)));
typedef float floatx4 __attribute__((ext_vector_type(4)));
typedef unsigned short ushortx4 __attribute__((ext_vector_type(4)));

__device__ inline float bf2f(unsigned short u) {
  return __uint_as_float(((unsigned)u) << 16);
}
__device__ inline unsigned short f2bf(float x) {
  unsigned u = __float_as_uint(x);
  u = (u + 0x7FFFu + ((u >> 16) & 1u)) >> 16;
  return (unsigned short)u;
}

// ---------------- dtype probe: bf16 vs fp32 inputs ----------------
__global__ void probe_kernel(const unsigned short* __restrict__ in, int* __restrict__ flag) {
  __shared__ float red[256];
  float m = 0.f;
  for (int i = threadIdx.x; i < 8192; i += 256) {
    float v = fabsf(bf2f(in[i]));
    if (!isnan(v)) m = fmaxf(m, v);
  }
  red[threadIdx.x] = m;
  __syncthreads();
  for (int s = 128; s > 0; s >>= 1) {
    if (threadIdx.x < s) red[threadIdx.x] = fmaxf(red[threadIdx.x], red[threadIdx.x + s]);
    __syncthreads();
  }
  if (threadIdx.x == 0) flag[0] = (red[0] < 1000.0f) ? 1 : 0;  // 1 = input is bf16
}

// ---------------- cast X -> bf16 (or copy) ----------------
__global__ __launch_bounds__(256) void cast_any(const void* __restrict__ in,
                                                unsigned short* __restrict__ out,
                                                const int* __restrict__ flag, int n) {
  int i = (blockIdx.x * 256 + threadIdx.x) * 4;
  if (i >= n) return;
  if (flag[0]) {
    *(ushortx4*)(out + i) = *(const ushortx4*)((const unsigned short*)in + i);
  } else {
    const float* f = (const float*)in + i;
    ushortx4 o;
    o.x = f2bf(f[0]); o.y = f2bf(f[1]); o.z = f2bf(f[2]); o.w = f2bf(f[3]);
    *(ushortx4*)(out + i) = o;
  }
}

// ---------------- transpose+cast W (K=4096 x N) -> WT[n][k] bf16 ----------------
__global__ __launch_bounds__(256) void transpose_cast(const void* __restrict__ W,
                                                      unsigned short* __restrict__ WT,
                                                      const int* __restrict__ flag,
                                                      int N, int rowOff) {
  __shared__ unsigned short tile[32][33];
  int n0 = blockIdx.x * 32, k0 = blockIdx.y * 32;
  int tx = threadIdx.x & 31, ty = threadIdx.x >> 5;
  bool isbf = flag[0] != 0;
#pragma unroll
  for (int p = 0; p < 4; ++p) {
    int k = k0 + ty + p * 8;
    size_t idx = (size_t)k * N + n0 + tx;
    unsigned short b = isbf ? ((const unsigned short*)W)[idx] : f2bf(((const float*)W)[idx]);
    tile[ty + p * 8][tx] = b;
  }
  __syncthreads();
#pragma unroll
  for (int p = 0; p < 4; ++p) {
    int n = n0 + ty + p * 8;
    WT[(size_t)(rowOff + n) * 4096 + k0 + tx] = tile[tx][ty + p * 8];
  }
}

// ---------------- bf16 MFMA GEMM: C[M,N] = A[M,K] * BT[N,K]^T ----------------
__device__ inline void gload16(const unsigned short* g, unsigned short* lds) {
  __builtin_amdgcn_global_load_lds(
      (const __attribute__((address_space(1))) unsigned int*)g,
      (__attribute__((address_space(3))) unsigned int*)lds, 16, 0, 0);
}

template <int OUTMODE>  // 0: bf16 out; 1: flag-selected (bf16 if flag else fp32)
__global__ __launch_bounds__(256) void gemm_bt(const unsigned short* __restrict__ A,
                                               const unsigned short* __restrict__ BT,
                                               void* __restrict__ C, int M, int N, int K,
                                               const int* __restrict__ flag) {
  __shared__ __attribute__((aligned(16))) unsigned short As[128 * 32];
  __shared__ __attribute__((aligned(16))) unsigned short Bs[128 * 32];
  int tid = threadIdx.x;
  int w = tid >> 6, l = tid & 63;
  int wm = w >> 1, wn = w & 1;
  int m0 = blockIdx.y * 128, n0 = blockIdx.x * 128;
  int lane15 = l & 15, quad = l >> 4;
  int rA = w * 16 + (l >> 2);
  int c8 = (l & 3) * 8;
  const unsigned short* Ab = A + (size_t)m0 * K;
  const unsigned short* Bb = BT + (size_t)n0 * K;
  floatx4 acc[4][4] = {};

  for (int k0 = 0; k0 < K; k0 += 32) {
#pragma unroll
    for (int p = 0; p < 2; ++p) {
      gload16(Ab + (size_t)(p * 64 + rA) * K + k0 + c8, &As[(p * 64 + w * 16) * 32]);
      gload16(Bb + (size_t)(p * 64 + rA) * K + k0 + c8, &Bs[(p * 64 + w * 16) * 32]);
    }
    __syncthreads();
    const unsigned short* pa = As + (wm * 64 + lane15) * 32 + quad * 8;
    const unsigned short* pb = Bs + (wn * 64 + lane15) * 32 + quad * 8;
    short8 af[4], bfr[4];
#pragma unroll
    for (int i = 0; i < 4; ++i) {
      af[i] = *(const short8*)(pa + i * 512);
      bfr[i] = *(const short8*)(pb + i * 512);
    }
#pragma unroll
    for (int mi = 0; mi < 4; ++mi)
#pragma unroll
      for (int ni = 0; ni < 4; ++ni)
        acc[mi][ni] = __builtin_amdgcn_mfma_f32_16x16x32_bf16(af[mi], bfr[ni], acc[mi][ni], 0, 0, 0);
    __syncthreads();
  }

  bool obf = true;
  if (OUTMODE == 1) obf = (flag[0] != 0);
#pragma unroll
  for (int mi = 0; mi < 4; ++mi) {
    int rbase = m0 + wm * 64 + mi * 16 + quad * 4;
#pragma unroll
    for (int ni = 0; ni < 4; ++ni) {
      int col = n0 + wn * 64 + ni * 16 + lane15;
#pragma unroll
      for (int rr = 0; rr < 4; ++rr) {
        float v = acc[mi][ni][rr];
        size_t idx = (size_t)(rbase + rr) * N + col;
        if (OUTMODE == 0 || obf)
          ((unsigned short*)C)[idx] = f2bf(v);
        else
          ((float*)C)[idx] = v;
      }
    }
  }
}

// ---------------- fused RoPE + head-softmax + PV per token ----------------
__global__ __launch_bounds__(256) void attn_kernel(const unsigned short* __restrict__ QKV,
                                                   unsigned short* __restrict__ AO) {
  __shared__ __attribute__((aligned(16))) float qr[32 * 136];
  __shared__ __attribute__((aligned(16))) float kr[8 * 136];
  __shared__ __attribute__((aligned(16))) float vv[8 * 136];
  __shared__ float P[256];
  __shared__ float sn[64], cs[64];
  int r = blockIdx.x;
  int pos = r & 4095;  // r = b*4096 + s
  int t = threadIdx.x;
  const unsigned short* row = QKV + (size_t)r * 6144;

  if (t < 64) {
    double e = pow(10000.0, (double)(2 * (t >> 1)) / 64.0);
    float f = (float)pos * (float)e;
    float s_, c_;
    sincosf(f, &s_, &c_);
    sn[t] = s_;
    cs[t] = c_;
  }
  __syncthreads();

  // K (RoPE'd) and V into LDS: 8 heads x 128
#pragma unroll
  for (int p = 0; p < 4; ++p) {
    int e = t + p * 256;
    int head = e >> 7, d = e & 127;
    float x = bf2f(row[4096 + e]);
    float xp = bf2f(row[4096 + (e ^ 64)]);
    float sg = (d < 64) ? -1.f : 1.f;
    kr[head * 136 + d] = x * cs[d & 63] + sg * xp * sn[d & 63];
    vv[head * 136 + d] = bf2f(row[5120 + e]);
  }
  // Q (RoPE'd) into LDS: 32 heads x 128
#pragma unroll
  for (int p = 0; p < 16; ++p) {
    int e = t + p * 256;
    int head = e >> 7, d = e & 127;
    float x = bf2f(row[e]);
    float xp = bf2f(row[e ^ 64]);
    float sg = (d < 64) ? -1.f : 1.f;
    qr[head * 136 + d] = x * cs[d & 63] + sg * xp * sn[d & 63];
  }
  __syncthreads();

  // scores: thread t -> (h = t>>3, j = t&7)
  int h = t >> 3, j = t & 7;
  const float4* q4 = (const float4*)(qr + h * 136);
  const float4* k4 = (const float4*)(kr + j * 136);
  float s = 0.f;
#pragma unroll
  for (int d4 = 0; d4 < 32; ++d4) {
    float4 a = q4[d4], b = k4[d4];
    s += a.x * b.x + a.y * b.y + a.z * b.z + a.w * b.w;
  }
  s *= 0.08838834764831845f;  // 1/sqrt(128)
  float mx = s;
  mx = fmaxf(mx, __shfl_xor(mx, 1));
  mx = fmaxf(mx, __shfl_xor(mx, 2));
  mx = fmaxf(mx, __shfl_xor(mx, 4));
  float ex = expf(s - mx);
  float sm = ex;
  sm += __shfl_xor(sm, 1);
  sm += __shfl_xor(sm, 2);
  sm += __shfl_xor(sm, 4);
  P[t] = ex / sm;
  __syncthreads();

  // out[h][d0..d0+16) = sum_j P[h][j] * v[j][d]
  int d0 = (t & 7) * 16;
  float o[16];
#pragma unroll
  for (int c = 0; c < 16; ++c) o[c] = 0.f;
#pragma unroll
  for (int j2 = 0; j2 < 8; ++j2) {
    float pj = P[h * 8 + j2];
    const float4* v4 = (const float4*)(vv + j2 * 136 + d0);
#pragma unroll
    for (int c = 0; c < 4; ++c) {
      float4 x = v4[c];
      o[c * 4 + 0] += pj * x.x;
      o[c * 4 + 1] += pj * x.y;
      o[c * 4 + 2] += pj * x.z;
      o[c * 4 + 3] += pj * x.w;
    }
  }
  unsigned short* outp = AO + (size_t)r * 4096 + h * 128 + d0;
#pragma unroll
  for (int c = 0; c < 4; ++c) {
    ushortx4 ov;
    ov.x = f2bf(o[c * 4 + 0]);
    ov.y = f2bf(o[c * 4 + 1]);
    ov.z = f2bf(o[c * 4 + 2]);
    ov.w = f2bf(o[c * 4 + 3]);
    *(ushortx4*)(outp + c * 4) = ov;
  }
}

extern "C" void kernel_launch(void* const* d_in, const int* in_sizes, int n_in,
                              void* d_out, int out_size, void* d_ws, size_t ws_size,
                              hipStream_t stream) {
  (void)in_sizes; (void)n_in; (void)out_size; (void)ws_size;
  const void* X  = d_in[0];
  const void* Wq = d_in[1];
  const void* Wk = d_in[2];
  const void* Wv = d_in[3];
  const void* Wo = d_in[4];
  char* ws = (char*)d_ws;
  unsigned short* Xb   = (unsigned short*)(ws);                 // 8192x4096 bf16
  unsigned short* WT   = (unsigned short*)(ws + 67108864);      // 6144x4096 bf16 (Wq|Wk|Wv)^T
  unsigned short* WoT  = (unsigned short*)(ws + 117440512);     // 4096x4096 bf16
  unsigned short* QKVb = (unsigned short*)(ws + 150994944);     // 8192x6144 bf16
  int* flag            = (int*)(ws + 251658240);
  unsigned short* AO = Xb;  // alias: Xb dead after gemm1

  probe_kernel<<<1, 256, 0, stream>>>((const unsigned short*)X, flag);
  cast_any<<<32768, 256, 0, stream>>>(X, Xb, flag, 33554432);
  transpose_cast<<<dim3(128, 128), 256, 0, stream>>>(Wq, WT, flag, 4096, 0);
  transpose_cast<<<dim3(32, 128), 256, 0, stream>>>(Wk, WT, flag, 1024, 4096);
  transpose_cast<<<dim3(32, 128), 256, 0, stream>>>(Wv, WT, flag, 1024, 5120);
  transpose_cast<<<dim3(128, 128), 256, 0, stream>>>(Wo, WoT, flag, 4096, 0);
  gemm_bt<0><<<dim3(48, 64), 256, 0, stream>>>(Xb, WT, QKVb, 8192, 6144, 4096, flag);
  attn_kernel<<<8192, 256, 0, stream>>>(QKVb, AO);
  gemm_bt<1><<<dim3(32, 64), 256, 0, stream>>>(AO, WoT, d_out, 8192, 4096, 4096, flag);
}